// Round 2
// baseline (560.734 us; speedup 1.0000x reference)
//
#include <hip/hip_runtime.h>
#include <hip/hip_bf16.h>
#include <stdint.h>

// AttentiveFP readout: B=2048 graphs x (48 real + 1 virtual) nodes, D=256, H=8, DH=32, 4 steps.
// Real-node rows evolve independently (x' = relu(x@Ws)); virtual/GRU state is the only
// sequential dependency. Per step, ONE fused kernel per graph computes x@[Wg;Ws] with a
// barrier-free global->reg MFMA k-loop, keeps h in LDS, and finishes attention in-block.

#define NEG_SLOPE 0.2f

typedef unsigned short u16;
typedef short s16x8 __attribute__((ext_vector_type(8)));
typedef float f32x4 __attribute__((ext_vector_type(4)));
typedef u16 u16x8 __attribute__((ext_vector_type(8)));
typedef u16 u16x4 __attribute__((ext_vector_type(4)));

__device__ __forceinline__ u16 f2bf(float f) {
  union { float f; uint32_t u; } v; v.f = f;
  uint32_t r = (v.u + 0x7FFFu + ((v.u >> 16) & 1u)) >> 16;  // RNE
  return (u16)r;
}
__device__ __forceinline__ float bf2f(u16 h) {
  union { uint32_t u; float f; } v; v.u = ((uint32_t)h) << 16;
  return v.f;
}

__device__ __forceinline__ void gload_lds16(const void* g, void* l) {
  __builtin_amdgcn_global_load_lds(
      (const __attribute__((address_space(1))) void*)g,
      (__attribute__((address_space(3))) void*)l, 16, 0, 0);
}

// ---------------------------------------------------------------------------
// FUSED step kernel: one block per graph.
//   Phase A: e_dst (hv . att_dst per head), cache att_src, hold sv in reg.
//   Phase B: O[48x512] = x_g @ [Wg;Ws]^T  -- barrier-free k-loop, a/b frags
//            loaded global->reg (A tile 24KB L1/L2-hot, W 256KB L2-hot).
//   Phase C: waves 0,1 -> h into LDS (stride 264); waves 2,3 -> relu -> Xn.
//   Phase D-F: e_src, leaky, softmax over 48, msg, g0 = relu(msg+sv) -> GS.
// ---------------------------------------------------------------------------
__global__ __launch_bounds__(256, 2)
void fused_step(const u16* __restrict__ X, const u16* __restrict__ W2T,
                const float* __restrict__ HVSV, const float* __restrict__ asrc,
                const float* __restrict__ adst, u16* __restrict__ GS,
                u16* __restrict__ Xn) {
  __shared__ u16 ldsH[48 * 264];
  __shared__ float ldsE[48 * 8];
  __shared__ float ldsEd[8];
  __shared__ float ldsAs[256];
  const int tid = threadIdx.x, b = blockIdx.x;
  const int w = tid >> 6, l = tid & 63, lr = l & 15, lk = l >> 4;

  // Phase A
  float sv = HVSV[(size_t)b * 512 + 256 + tid];
  ldsAs[tid] = asrc[tid];
  {
    float pd = HVSV[(size_t)b * 512 + tid] * adst[tid];
    pd += __shfl_xor(pd, 16); pd += __shfl_xor(pd, 8);
    pd += __shfl_xor(pd, 4);  pd += __shfl_xor(pd, 2);
    pd += __shfl_xor(pd, 1);
    if ((tid & 31) == 0) ldsEd[tid >> 5] = pd;
  }

  // Phase B: GEMM. Wave w covers cols [w*128, w*128+128) of N=512.
  const u16* Ab = X + ((size_t)b * 48 + lr) * 256 + lk * 8;
  const u16* Bb = W2T + ((size_t)w * 128 + lr) * 256 + lk * 8;
  f32x4 acc[3][8];
#pragma unroll
  for (int i = 0; i < 3; ++i)
#pragma unroll
    for (int j = 0; j < 8; ++j) acc[i][j] = (f32x4){0.f, 0.f, 0.f, 0.f};

  s16x8 a0[3], a1[3], b0[8], b1[8];
#define LD_AB(K, AR, BR)                                                      \
  {                                                                           \
    _Pragma("unroll") for (int mi = 0; mi < 3; ++mi)                          \
        AR[mi] = *(const s16x8*)(Ab + mi * 4096 + (K) * 32);                  \
    _Pragma("unroll") for (int ni = 0; ni < 8; ++ni)                          \
        BR[ni] = *(const s16x8*)(Bb + ni * 4096 + (K) * 32);                  \
  }
#define DO_MFMA(AR, BR)                                                       \
  {                                                                           \
    _Pragma("unroll") for (int mi = 0; mi < 3; ++mi)                          \
        _Pragma("unroll") for (int ni = 0; ni < 8; ++ni)                      \
        acc[mi][ni] = __builtin_amdgcn_mfma_f32_16x16x32_bf16(                \
            AR[mi], BR[ni], acc[mi][ni], 0, 0, 0);                            \
  }
  LD_AB(0, a0, b0);
#pragma unroll
  for (int kk = 0; kk < 8; ++kk) {
    if ((kk & 1) == 0) {
      if (kk < 7) LD_AB(kk + 1, a1, b1);
      DO_MFMA(a0, b0);
    } else {
      if (kk < 7) LD_AB(kk + 1, a0, b0);
      DO_MFMA(a1, b1);
    }
  }
#undef LD_AB
#undef DO_MFMA

  // Phase C: epilogue split by wave role.
  if (w >= 2) {
#pragma unroll
    for (int mi = 0; mi < 3; ++mi)
#pragma unroll
      for (int ni = 0; ni < 8; ++ni) {
        int rg = b * 48 + mi * 16 + lk * 4;
        int c = (w - 2) * 128 + ni * 16 + lr;
#pragma unroll
        for (int j = 0; j < 4; ++j)
          Xn[(size_t)(rg + j) * 256 + c] = f2bf(fmaxf(acc[mi][ni][j], 0.f));
      }
  } else {
#pragma unroll
    for (int mi = 0; mi < 3; ++mi)
#pragma unroll
      for (int ni = 0; ni < 8; ++ni) {
        int r = mi * 16 + lk * 4;
        int c = w * 128 + ni * 16 + lr;
#pragma unroll
        for (int j = 0; j < 4; ++j)
          ldsH[(r + j) * 264 + c] = f2bf(acc[mi][ni][j]);
      }
  }
  __syncthreads();

  // Phase D: e_src + leaky_relu
  for (int idx = tid; idx < 48 * 8; idx += 256) {
    int s = idx >> 3, hh = idx & 7;
    const u16* hr = &ldsH[s * 264 + hh * 32];
    float e = 0.f;
#pragma unroll
    for (int d2 = 0; d2 < 32; ++d2) e += bf2f(hr[d2]) * ldsAs[hh * 32 + d2];
    e += ldsEd[hh];
    ldsE[s * 8 + hh] = (e > 0.f) ? e : NEG_SLOPE * e;
  }
  __syncthreads();

  // Phase E: softmax over s (8 heads, serial-by-head; tiny)
  if (tid < 8) {
    float mx = -1e30f;
    for (int s = 0; s < 48; ++s) mx = fmaxf(mx, ldsE[s * 8 + tid]);
    float sum = 0.f;
    for (int s = 0; s < 48; ++s) {
      float ex = expf(ldsE[s * 8 + tid] - mx);
      ldsE[s * 8 + tid] = ex; sum += ex;
    }
    float inv = 1.f / sum;
    for (int s = 0; s < 48; ++s) ldsE[s * 8 + tid] *= inv;
  }
  __syncthreads();

  // Phase F: msg + g0
  {
    int d = tid, hh = d >> 5;
    float m = 0.f;
    for (int s = 0; s < 48; ++s) m += ldsE[s * 8 + hh] * bf2f(ldsH[s * 264 + d]);
    GS[(size_t)b * 512 + d] = f2bf(fmaxf(m + sv, 0.f));
  }
}

// ---------------------------------------------------------------------------
// Generic bf16 GEMM (small M): C[M,N] = A[M,K=256] * Bt[N,K=256]^T, 128x128.
// EPI: 0 = f32 store; 2 = f32 + bias.
// ---------------------------------------------------------------------------
template<int EPI>
__global__ __launch_bounds__(256)
void gemm_bt(const u16* __restrict__ A, int lda,
             const u16* __restrict__ Bt,
             float* __restrict__ Cf, int ldc, const float* __restrict__ bias) {
  __shared__ u16 ldsA[2 * 128 * 32];
  __shared__ u16 ldsB[2 * 128 * 32];
  const int tid = threadIdx.x;
  const int w = tid >> 6;
  const int l = tid & 63;
  const int wr = w >> 1, wc = w & 1;
  const int lr = l & 15, lk = l >> 4;
  const int m0 = blockIdx.x * 128, n0 = blockIdx.y * 128;

  f32x4 acc[4][4];
#pragma unroll
  for (int i = 0; i < 4; ++i)
#pragma unroll
    for (int j = 0; j < 4; ++j) acc[i][j] = (f32x4){0.f, 0.f, 0.f, 0.f};

  for (int kt = 0; kt < 4; ++kt) {
    const u16* Ag = A + (size_t)m0 * lda + kt * 64;
    const u16* Bg = Bt + (size_t)n0 * 256 + kt * 64;
#pragma unroll
    for (int i = 0; i < 4; ++i) {
      int q = i * 256 + tid;
      int h2 = q >> 9;
      int r  = (q >> 2) & 127;
      int c4 = q & 3;
      gload_lds16(Ag + (size_t)r * lda + h2 * 32 + c4 * 8,
                  &ldsA[(i * 256 + w * 64) * 8]);
      gload_lds16(Bg + (size_t)r * 256 + h2 * 32 + c4 * 8,
                  &ldsB[(i * 256 + w * 64) * 8]);
    }
    __syncthreads();
#pragma unroll
    for (int kk = 0; kk < 64; kk += 32) {
      const int hb = (kk >> 5) * 4096;
      s16x8 af[4], bfr[4];
#pragma unroll
      for (int mi = 0; mi < 4; ++mi)
        af[mi] = *(const s16x8*)&ldsA[hb + (wr * 64 + mi * 16 + lr) * 32 + lk * 8];
#pragma unroll
      for (int ni = 0; ni < 4; ++ni)
        bfr[ni] = *(const s16x8*)&ldsB[hb + (wc * 64 + ni * 16 + lr) * 32 + lk * 8];
#pragma unroll
      for (int mi = 0; mi < 4; ++mi)
#pragma unroll
        for (int ni = 0; ni < 4; ++ni)
          acc[mi][ni] = __builtin_amdgcn_mfma_f32_16x16x32_bf16(af[mi], bfr[ni], acc[mi][ni], 0, 0, 0);
    }
    __syncthreads();
  }

#pragma unroll
  for (int mi = 0; mi < 4; ++mi) {
#pragma unroll
    for (int ni = 0; ni < 4; ++ni) {
      f32x4 v = acc[mi][ni];
      int r = m0 + wr * 64 + mi * 16 + lk * 4;
      int c = n0 + wc * 64 + ni * 16 + lr;
#pragma unroll
      for (int j = 0; j < 4; ++j) {
        float fv = v[j];
        if (EPI == 0) Cf[(size_t)(r + j) * ldc + c] = fv;
        else          Cf[(size_t)(r + j) * ldc + c] = fv + bias[c];
      }
    }
  }
}

// Merged GRU-gate GEMM: blockIdx.y<6 -> G1 = g0@wx ; else G2 = state@wh.
__global__ __launch_bounds__(256)
void gemm_gates(const u16* __restrict__ GS, const u16* __restrict__ WXT,
                const u16* __restrict__ WHT, float* __restrict__ G1,
                float* __restrict__ G2) {
  __shared__ u16 ldsA[2 * 128 * 32];
  __shared__ u16 ldsB[2 * 128 * 32];
  const bool second = blockIdx.y >= 6;
  const u16* A = GS + (second ? 256 : 0);
  const u16* Bt = second ? WHT : WXT;
  float* Cf = second ? G2 : G1;
  const int n0 = (second ? blockIdx.y - 6 : blockIdx.y) * 128;
  const int m0 = blockIdx.x * 128;
  const int tid = threadIdx.x;
  const int w = tid >> 6;
  const int l = tid & 63;
  const int wr = w >> 1, wc = w & 1;
  const int lr = l & 15, lk = l >> 4;

  f32x4 acc[4][4];
#pragma unroll
  for (int i = 0; i < 4; ++i)
#pragma unroll
    for (int j = 0; j < 4; ++j) acc[i][j] = (f32x4){0.f, 0.f, 0.f, 0.f};

  for (int kt = 0; kt < 4; ++kt) {
    const u16* Ag = A + (size_t)m0 * 512 + kt * 64;
    const u16* Bg = Bt + (size_t)n0 * 256 + kt * 64;
#pragma unroll
    for (int i = 0; i < 4; ++i) {
      int q = i * 256 + tid;
      int h2 = q >> 9;
      int r  = (q >> 2) & 127;
      int c4 = q & 3;
      gload_lds16(Ag + (size_t)r * 512 + h2 * 32 + c4 * 8,
                  &ldsA[(i * 256 + w * 64) * 8]);
      gload_lds16(Bg + (size_t)r * 256 + h2 * 32 + c4 * 8,
                  &ldsB[(i * 256 + w * 64) * 8]);
    }
    __syncthreads();
#pragma unroll
    for (int kk = 0; kk < 64; kk += 32) {
      const int hb = (kk >> 5) * 4096;
      s16x8 af[4], bfr[4];
#pragma unroll
      for (int mi = 0; mi < 4; ++mi)
        af[mi] = *(const s16x8*)&ldsA[hb + (wr * 64 + mi * 16 + lr) * 32 + lk * 8];
#pragma unroll
      for (int ni = 0; ni < 4; ++ni)
        bfr[ni] = *(const s16x8*)&ldsB[hb + (wc * 64 + ni * 16 + lr) * 32 + lk * 8];
#pragma unroll
      for (int mi = 0; mi < 4; ++mi)
#pragma unroll
        for (int ni = 0; ni < 4; ++ni)
          acc[mi][ni] = __builtin_amdgcn_mfma_f32_16x16x32_bf16(af[mi], bfr[ni], acc[mi][ni], 0, 0, 0);
    }
    __syncthreads();
  }

#pragma unroll
  for (int mi = 0; mi < 4; ++mi) {
#pragma unroll
    for (int ni = 0; ni < 4; ++ni) {
      f32x4 v = acc[mi][ni];
      int r = m0 + wr * 64 + mi * 16 + lk * 4;
      int c = n0 + wc * 64 + ni * 16 + lr;
#pragma unroll
      for (int j = 0; j < 4; ++j)
        Cf[(size_t)(r + j) * 768 + c] = v[j];
    }
  }
}

// One-shot transpose-convert of all weights: out[N][K] bf16 from in[K][N] f32.
__global__ void tcvt_all(const float* __restrict__ Wg, const float* __restrict__ Ws,
                         const float* __restrict__ wx, const float* __restrict__ wh,
                         const float* __restrict__ pw,
                         u16* __restrict__ W2T, u16* __restrict__ WXT,
                         u16* __restrict__ WHT, u16* __restrict__ PRJ) {
  int idx = blockIdx.x * 256 + threadIdx.x;
  const float* src; u16* dst; int N; int li;
  if (idx < 65536)        { src = Wg; dst = W2T;          N = 256; li = idx; }
  else if (idx < 131072)  { src = Ws; dst = W2T + 65536;  N = 256; li = idx - 65536; }
  else if (idx < 327680)  { src = wx; dst = WXT;          N = 768; li = idx - 131072; }
  else if (idx < 524288)  { src = wh; dst = WHT;          N = 768; li = idx - 327680; }
  else                    { src = pw; dst = PRJ;          N = 256; li = idx - 524288; }
  int n = li >> 8, k = li & 255;
  dst[li] = f2bf(src[(size_t)k * N + n]);
}

// x0 bf16 + virtual sum -> state f32 + GS state half (bf16). float4 loads, 8B stores.
__global__ __launch_bounds__(256)
void prep_x_kernel(const float* __restrict__ nf, u16* __restrict__ X0,
                   float* __restrict__ state, u16* __restrict__ GS) {
  __shared__ f32x4 part[4][64];
  const int b = blockIdx.x, t = threadIdx.x;
  const int c4 = t & 63, sg = t >> 6;
  const f32x4* src = (const f32x4*)(nf + (size_t)b * 48 * 256);
  f32x4 acc = (f32x4){0.f, 0.f, 0.f, 0.f};
  for (int s = sg * 12; s < sg * 12 + 12; ++s) {
    f32x4 v = src[(size_t)s * 64 + c4];
    acc += v;
    u16x4 o = {f2bf(v[0]), f2bf(v[1]), f2bf(v[2]), f2bf(v[3])};
    *(u16x4*)(X0 + ((size_t)b * 48 + s) * 256 + c4 * 4) = o;
  }
  part[sg][c4] = acc;
  __syncthreads();
  if (t < 64) {
    f32x4 r = part[0][t] + part[1][t] + part[2][t] + part[3][t];
#pragma unroll
    for (int j = 0; j < 4; ++j) {
      int d = t * 4 + j;
      state[(size_t)b * 256 + d] = r[j];
      GS[(size_t)b * 512 + 256 + d] = f2bf(r[j]);
    }
  }
}

// GRU elementwise
__global__ void gru_kernel(const float* __restrict__ G1, const float* __restrict__ G2,
                           const float* __restrict__ bx, const float* __restrict__ bh,
                           float* __restrict__ state, u16* __restrict__ GS) {
  const int b = blockIdx.x, d = threadIdx.x;
  const float* g1 = G1 + (size_t)b * 768;
  const float* g2 = G2 + (size_t)b * 768;
  float xz = g1[d] + bx[d], xr = g1[256 + d] + bx[256 + d], xh = g1[512 + d] + bx[512 + d];
  float hz = g2[d] + bh[d], hr = g2[256 + d] + bh[256 + d], hh2 = g2[512 + d] + bh[512 + d];
  float z = 1.f / (1.f + expf(-(xz + hz)));
  float r = 1.f / (1.f + expf(-(xr + hr)));
  float n = tanhf(xh + r * hh2);
  float h0 = state[b * 256 + d];
  float sn = z * h0 + (1.f - z) * n;
  state[b * 256 + d] = sn;
  GS[(size_t)b * 512 + 256 + d] = f2bf(sn);
}

extern "C" void kernel_launch(void* const* d_in, const int* in_sizes, int n_in,
                              void* d_out, int out_size, void* d_ws, size_t ws_size,
                              hipStream_t stream) {
  const float* nf  = (const float*)d_in[0];
  const float* Wg  = (const float*)d_in[2];
  const float* Ws  = (const float*)d_in[3];
  const float* asr = (const float*)d_in[4];
  const float* ads = (const float*)d_in[5];
  const float* wx  = (const float*)d_in[6];
  const float* wh  = (const float*)d_in[7];
  const float* bx  = (const float*)d_in[8];
  const float* bh  = (const float*)d_in[9];
  const float* pw  = (const float*)d_in[10];
  const float* pb  = (const float*)d_in[11];
  float* out = (float*)d_out;

  char* p = (char*)d_ws;
  size_t off = 0;
  auto alloc = [&](size_t bytes) { char* r = p + off; off += (bytes + 255) & ~255ULL; return r; };
  u16* W2T   = (u16*)alloc(512 * 256 * 2);
  u16* WXT   = (u16*)alloc(768 * 256 * 2);
  u16* WHT   = (u16*)alloc(768 * 256 * 2);
  u16* PRJ   = (u16*)alloc(256 * 256 * 2);
  u16* X0    = (u16*)alloc((size_t)98304 * 256 * 2);
  u16* X1    = (u16*)alloc((size_t)98304 * 256 * 2);
  float* HVSV = (float*)alloc((size_t)2048 * 512 * 4);
  float* G1   = (float*)alloc((size_t)2048 * 768 * 4);
  float* G2   = (float*)alloc((size_t)2048 * 768 * 4);
  u16* GS     = (u16*)alloc((size_t)2048 * 512 * 2);
  float* ST   = (float*)alloc((size_t)2048 * 256 * 4);

  tcvt_all<<<2304, 256, 0, stream>>>(Wg, Ws, wx, wh, pw, W2T, WXT, WHT, PRJ);
  prep_x_kernel<<<2048, 256, 0, stream>>>(nf, X0, ST, GS);

  u16* xc = X0; u16* xn = X1;
  for (int t = 0; t < 4; ++t) {
    // hv = state@Wg, sv = state@Ws   (M=2048, N=512)
    gemm_bt<0><<<dim3(16, 4), 256, 0, stream>>>(GS + 256, 512, W2T, HVSV, 512, nullptr);
    // fused: h+attention+g0 and xnext
    fused_step<<<2048, 256, 0, stream>>>(xc, W2T, HVSV, asr, ads, GS, xn);
    // GRU gates (both in one launch)
    gemm_gates<<<dim3(16, 12), 256, 0, stream>>>(GS, WXT, WHT, G1, G2);
    gru_kernel<<<2048, 256, 0, stream>>>(G1, G2, bx, bh, ST, GS);
    u16* tmp = xc; xc = xn; xn = tmp;
  }
  // out = state @ proj_w + proj_b
  gemm_bt<2><<<dim3(16, 2), 256, 0, stream>>>(GS + 256, 512, PRJ, out, 256, pb);
}

// Round 3
// 318.373 us; speedup vs baseline: 1.7612x; 1.7612x over previous
//
#include <hip/hip_runtime.h>
#include <hip/hip_bf16.h>
#include <stdint.h>

// AttentiveFP readout: B=2048 graphs x (48 real + 1 virtual) nodes, D=256, H=8, DH=32, 4 steps.
// Fused per-graph step kernel: A-tile (48 node rows + state row 48) staged once in LDS;
// B (=[Wg;Ws]^T) staged per (n-chunk,k-tile) via global_load_lds (round-1-proven pipeline);
// attention done fully in registers via shfl butterflies (each wave's 32-col slice = 1 head).

#define NEG_SLOPE 0.2f

typedef unsigned short u16;
typedef short s16x8 __attribute__((ext_vector_type(8)));
typedef float f32x4 __attribute__((ext_vector_type(4)));
typedef u16 u16x8 __attribute__((ext_vector_type(8)));
typedef u16 u16x4 __attribute__((ext_vector_type(4)));

__device__ __forceinline__ u16 f2bf(float f) {
  union { float f; uint32_t u; } v; v.f = f;
  uint32_t r = (v.u + 0x7FFFu + ((v.u >> 16) & 1u)) >> 16;  // RNE
  return (u16)r;
}
__device__ __forceinline__ float bf2f(u16 h) {
  union { uint32_t u; float f; } v; v.u = ((uint32_t)h) << 16;
  return v.f;
}

__device__ __forceinline__ void gload_lds16(const void* g, void* l) {
  __builtin_amdgcn_global_load_lds(
      (const __attribute__((address_space(1))) void*)g,
      (__attribute__((address_space(3))) void*)l, 16, 0, 0);
}

__device__ __forceinline__ float redsum_lr(float v) {
  v += __shfl_xor(v, 1); v += __shfl_xor(v, 2);
  v += __shfl_xor(v, 4); v += __shfl_xor(v, 8);
  return v;
}
__device__ __forceinline__ float redsum_lk(float v) {
  v += __shfl_xor(v, 16); v += __shfl_xor(v, 32);
  return v;
}
__device__ __forceinline__ float redmax_lk(float v) {
  v = fmaxf(v, __shfl_xor(v, 16)); v = fmaxf(v, __shfl_xor(v, 32));
  return v;
}

// ---------------------------------------------------------------------------
// FUSED step: one block (4 waves) per graph.
//   A LDS [8 kc][64 r][32 k] (32KB): rows 0-47 = x_g, rows 48-63 = state row dup.
//   Loop n-chunks {2,3,0,1} x k-tiles: stage B [2][128][32] (16KB) -> sync ->
//   16 MFMA/wave -> sync.  Chunk 2,3 epilogue: relu->Xn + save sv (row 48).
//   Chunk 0,1 epilogue: pack h to bf16 regs + save hv (row 48).
//   Attention: per-wave in-register (wave w owns heads w and w+4), shfl reductions.
// ---------------------------------------------------------------------------
__global__ __launch_bounds__(256, 3)
void fused_step(const u16* __restrict__ X, const u16* __restrict__ W2T,
                const float* __restrict__ asrc, const float* __restrict__ adst,
                u16* __restrict__ GS, u16* __restrict__ Xn) {
  __shared__ u16 ldsA[8 * 64 * 32];   // 32 KB
  __shared__ u16 ldsB[2 * 128 * 32];  // 16 KB
  const int tid = threadIdx.x, b = blockIdx.x;
  const int w = tid >> 6, l = tid & 63, lr = l & 15, lk = l >> 4;
  const u16* Xg = X + (size_t)b * 48 * 256;
  const u16* Sg = GS + (size_t)b * 512 + 256;  // state row (bf16)

  // Stage A once: 2048 16B-chunks, layout chunk q -> (kc=q>>8, r=(q>>2)&63, c4=q&3)
#pragma unroll
  for (int i = 0; i < 8; ++i) {
    int q = i * 256 + tid;
    int kc = q >> 8, r = (q >> 2) & 63, c4 = q & 3;
    const u16* src = (r < 48 ? Xg + r * 256 : Sg) + kc * 32 + c4 * 8;
    gload_lds16(src, &ldsA[(i * 256 + w * 64) * 8]);
  }

  // Per-lane attention params: wave w owns head w (chunk 0) and head w+4 (chunk 1)
  float as_[2][2], ad_[2][2];
#pragma unroll
  for (int nc = 0; nc < 2; ++nc) {
    int head = w + nc * 4;
#pragma unroll
    for (int ni = 0; ni < 2; ++ni) {
      as_[nc][ni] = asrc[head * 32 + ni * 16 + lr];
      ad_[nc][ni] = adst[head * 32 + ni * 16 + lr];
    }
  }

  u16x4 hb[2][3][2];  // packed h fragments (rows lk*4+j, col ni*16+lr, per chunk)
  float hv_[2][2];    // virtual-h (row 48), valid on lk==0 lanes
  float sv_[2][2];    // state@Ws row (row 48 of chunks 2,3), valid on lk==0 lanes

#define NC_BLOCK(NC, ISX)                                                          \
  {                                                                                \
    f32x4 acc[4][2];                                                               \
    _Pragma("unroll") for (int mi = 0; mi < 4; ++mi)                               \
      _Pragma("unroll") for (int ni = 0; ni < 2; ++ni)                             \
        acc[mi][ni] = (f32x4){0.f, 0.f, 0.f, 0.f};                                 \
    _Pragma("unroll") for (int kt = 0; kt < 4; ++kt) {                             \
      const u16* Bg = W2T + ((size_t)(NC)*128) * 256 + kt * 64;                    \
      _Pragma("unroll") for (int i = 0; i < 4; ++i) {                              \
        int q = i * 256 + tid;                                                     \
        int h2 = q >> 9, rr = (q >> 2) & 127, c4 = q & 3;                          \
        gload_lds16(Bg + (size_t)rr * 256 + h2 * 32 + c4 * 8,                      \
                    &ldsB[(i * 256 + w * 64) * 8]);                                \
      }                                                                            \
      __syncthreads();                                                             \
      _Pragma("unroll") for (int hh = 0; hh < 2; ++hh) {                           \
        const int kc = kt * 2 + hh;                                                \
        s16x8 af[4], bfr[2];                                                       \
        _Pragma("unroll") for (int mi = 0; mi < 4; ++mi)                           \
          af[mi] = *(const s16x8*)&ldsA[(kc * 64 + mi * 16 + lr) * 32 + lk * 8];   \
        _Pragma("unroll") for (int ni = 0; ni < 2; ++ni)                           \
          bfr[ni] = *(const s16x8*)&ldsB[(hh * 128 + w * 32 + ni * 16 + lr) * 32 + \
                                         lk * 8];                                  \
        _Pragma("unroll") for (int mi = 0; mi < 4; ++mi)                           \
          _Pragma("unroll") for (int ni = 0; ni < 2; ++ni)                         \
            acc[mi][ni] = __builtin_amdgcn_mfma_f32_16x16x32_bf16(                 \
                af[mi], bfr[ni], acc[mi][ni], 0, 0, 0);                            \
      }                                                                            \
      __syncthreads();                                                             \
    }                                                                              \
    if (ISX) {                                                                     \
      if (Xn) {                                                                    \
        _Pragma("unroll") for (int mi = 0; mi < 3; ++mi)                           \
          _Pragma("unroll") for (int ni = 0; ni < 2; ++ni)                         \
            _Pragma("unroll") for (int j = 0; j < 4; ++j)                          \
              Xn[(size_t)(b * 48 + mi * 16 + lk * 4 + j) * 256 +                   \
                 ((NC)-2) * 128 + w * 32 + ni * 16 + lr] =                         \
                  f2bf(fmaxf(acc[mi][ni][j], 0.f));                                \
      }                                                                            \
      _Pragma("unroll") for (int ni = 0; ni < 2; ++ni)                             \
        sv_[(NC)-2][ni] = acc[3][ni][0];                                           \
    } else {                                                                       \
      _Pragma("unroll") for (int mi = 0; mi < 3; ++mi)                             \
        _Pragma("unroll") for (int ni = 0; ni < 2; ++ni)                           \
          hb[(NC)][mi][ni] =                                                       \
              (u16x4){f2bf(acc[mi][ni][0]), f2bf(acc[mi][ni][1]),                  \
                      f2bf(acc[mi][ni][2]), f2bf(acc[mi][ni][3])};                 \
      _Pragma("unroll") for (int ni = 0; ni < 2; ++ni)                             \
        hv_[(NC)][ni] = acc[3][ni][0];                                             \
    }                                                                              \
  }

  NC_BLOCK(2, true)
  NC_BLOCK(3, true)
  NC_BLOCK(0, false)
  NC_BLOCK(1, false)
#undef NC_BLOCK

  // ---- In-register attention ----
  // e_dst per head: hv (row 48, lk==0 lanes) dot att_dst, full butterfly.
  float ed[2];
#pragma unroll
  for (int nc = 0; nc < 2; ++nc) {
    float p = 0.f;
    if (lk == 0) p = hv_[nc][0] * ad_[nc][0] + hv_[nc][1] * ad_[nc][1];
    ed[nc] = redsum_lk(redsum_lr(p));
  }

#pragma unroll
  for (int nc = 0; nc < 2; ++nc) {
    float al[3][4];
    float m = -1e30f;
#pragma unroll
    for (int mi = 0; mi < 3; ++mi)
#pragma unroll
      for (int j = 0; j < 4; ++j) {
        float p = bf2f(hb[nc][mi][0][j]) * as_[nc][0] +
                  bf2f(hb[nc][mi][1][j]) * as_[nc][1];
        p = redsum_lr(p) + ed[nc];               // e_src + e_dst, summed over 32 dims
        p = (p > 0.f) ? p : NEG_SLOPE * p;       // leaky_relu
        al[mi][j] = p;
        m = fmaxf(m, p);
      }
    m = redmax_lk(m);                            // max over all 48 nodes
    float s = 0.f;
#pragma unroll
    for (int mi = 0; mi < 3; ++mi)
#pragma unroll
      for (int j = 0; j < 4; ++j) {
        float ex = expf(al[mi][j] - m);
        al[mi][j] = ex; s += ex;
      }
    s = redsum_lk(s);                            // softmax denom over 48 nodes
    float inv = 1.f / s;
#pragma unroll
    for (int ni = 0; ni < 2; ++ni) {
      float mm = 0.f;
#pragma unroll
      for (int mi = 0; mi < 3; ++mi)
#pragma unroll
        for (int j = 0; j < 4; ++j)
          mm += al[mi][j] * bf2f(hb[nc][mi][ni][j]);
      mm = redsum_lk(mm) * inv;                  // msg over 48 nodes
      if (lk == 0)
        GS[(size_t)b * 512 + nc * 128 + w * 32 + ni * 16 + lr] =
            f2bf(fmaxf(mm + sv_[nc][ni], 0.f));  // g0 = relu(msg + sv)
    }
  }
}

// ---------------------------------------------------------------------------
// Generic bf16 GEMM (small M): C[M,N] = A[M,K=256] * Bt[N,K=256]^T, 128x128.
// EPI: 2 = f32 + bias (projection).
// ---------------------------------------------------------------------------
template<int EPI>
__global__ __launch_bounds__(256)
void gemm_bt(const u16* __restrict__ A, int lda,
             const u16* __restrict__ Bt,
             float* __restrict__ Cf, int ldc, const float* __restrict__ bias) {
  __shared__ u16 ldsA[2 * 128 * 32];
  __shared__ u16 ldsB[2 * 128 * 32];
  const int tid = threadIdx.x;
  const int w = tid >> 6;
  const int l = tid & 63;
  const int wr = w >> 1, wc = w & 1;
  const int lr = l & 15, lk = l >> 4;
  const int m0 = blockIdx.x * 128, n0 = blockIdx.y * 128;

  f32x4 acc[4][4];
#pragma unroll
  for (int i = 0; i < 4; ++i)
#pragma unroll
    for (int j = 0; j < 4; ++j) acc[i][j] = (f32x4){0.f, 0.f, 0.f, 0.f};

  for (int kt = 0; kt < 4; ++kt) {
    const u16* Ag = A + (size_t)m0 * lda + kt * 64;
    const u16* Bg = Bt + (size_t)n0 * 256 + kt * 64;
#pragma unroll
    for (int i = 0; i < 4; ++i) {
      int q = i * 256 + tid;
      int h2 = q >> 9;
      int r  = (q >> 2) & 127;
      int c4 = q & 3;
      gload_lds16(Ag + (size_t)r * lda + h2 * 32 + c4 * 8,
                  &ldsA[(i * 256 + w * 64) * 8]);
      gload_lds16(Bg + (size_t)r * 256 + h2 * 32 + c4 * 8,
                  &ldsB[(i * 256 + w * 64) * 8]);
    }
    __syncthreads();
#pragma unroll
    for (int kk = 0; kk < 64; kk += 32) {
      const int hb = (kk >> 5) * 4096;
      s16x8 af[4], bfr[4];
#pragma unroll
      for (int mi = 0; mi < 4; ++mi)
        af[mi] = *(const s16x8*)&ldsA[hb + (wr * 64 + mi * 16 + lr) * 32 + lk * 8];
#pragma unroll
      for (int ni = 0; ni < 4; ++ni)
        bfr[ni] = *(const s16x8*)&ldsB[hb + (wc * 64 + ni * 16 + lr) * 32 + lk * 8];
#pragma unroll
      for (int mi = 0; mi < 4; ++mi)
#pragma unroll
        for (int ni = 0; ni < 4; ++ni)
          acc[mi][ni] = __builtin_amdgcn_mfma_f32_16x16x32_bf16(af[mi], bfr[ni], acc[mi][ni], 0, 0, 0);
    }
    __syncthreads();
  }

#pragma unroll
  for (int mi = 0; mi < 4; ++mi) {
#pragma unroll
    for (int ni = 0; ni < 4; ++ni) {
      f32x4 v = acc[mi][ni];
      int r = m0 + wr * 64 + mi * 16 + lk * 4;
      int c = n0 + wc * 64 + ni * 16 + lr;
#pragma unroll
      for (int j = 0; j < 4; ++j) {
        float fv = v[j];
        if (EPI == 0) Cf[(size_t)(r + j) * ldc + c] = fv;
        else          Cf[(size_t)(r + j) * ldc + c] = fv + bias[c];
      }
    }
  }
}

// Merged GRU-gate GEMM: blockIdx.y<6 -> G1 = g0@wx ; else G2 = state@wh.
__global__ __launch_bounds__(256)
void gemm_gates(const u16* __restrict__ GS, const u16* __restrict__ WXT,
                const u16* __restrict__ WHT, float* __restrict__ G1,
                float* __restrict__ G2) {
  __shared__ u16 ldsA[2 * 128 * 32];
  __shared__ u16 ldsB[2 * 128 * 32];
  const bool second = blockIdx.y >= 6;
  const u16* A = GS + (second ? 256 : 0);
  const u16* Bt = second ? WHT : WXT;
  float* Cf = second ? G2 : G1;
  const int n0 = (second ? blockIdx.y - 6 : blockIdx.y) * 128;
  const int m0 = blockIdx.x * 128;
  const int tid = threadIdx.x;
  const int w = tid >> 6;
  const int l = tid & 63;
  const int wr = w >> 1, wc = w & 1;
  const int lr = l & 15, lk = l >> 4;

  f32x4 acc[4][4];
#pragma unroll
  for (int i = 0; i < 4; ++i)
#pragma unroll
    for (int j = 0; j < 4; ++j) acc[i][j] = (f32x4){0.f, 0.f, 0.f, 0.f};

  for (int kt = 0; kt < 4; ++kt) {
    const u16* Ag = A + (size_t)m0 * 512 + kt * 64;
    const u16* Bg = Bt + (size_t)n0 * 256 + kt * 64;
#pragma unroll
    for (int i = 0; i < 4; ++i) {
      int q = i * 256 + tid;
      int h2 = q >> 9;
      int r  = (q >> 2) & 127;
      int c4 = q & 3;
      gload_lds16(Ag + (size_t)r * 512 + h2 * 32 + c4 * 8,
                  &ldsA[(i * 256 + w * 64) * 8]);
      gload_lds16(Bg + (size_t)r * 256 + h2 * 32 + c4 * 8,
                  &ldsB[(i * 256 + w * 64) * 8]);
    }
    __syncthreads();
#pragma unroll
    for (int kk = 0; kk < 64; kk += 32) {
      const int hb = (kk >> 5) * 4096;
      s16x8 af[4], bfr[4];
#pragma unroll
      for (int mi = 0; mi < 4; ++mi)
        af[mi] = *(const s16x8*)&ldsA[hb + (wr * 64 + mi * 16 + lr) * 32 + lk * 8];
#pragma unroll
      for (int ni = 0; ni < 4; ++ni)
        bfr[ni] = *(const s16x8*)&ldsB[hb + (wc * 64 + ni * 16 + lr) * 32 + lk * 8];
#pragma unroll
      for (int mi = 0; mi < 4; ++mi)
#pragma unroll
        for (int ni = 0; ni < 4; ++ni)
          acc[mi][ni] = __builtin_amdgcn_mfma_f32_16x16x32_bf16(af[mi], bfr[ni], acc[mi][ni], 0, 0, 0);
    }
    __syncthreads();
  }

#pragma unroll
  for (int mi = 0; mi < 4; ++mi) {
#pragma unroll
    for (int ni = 0; ni < 4; ++ni) {
      f32x4 v = acc[mi][ni];
      int r = m0 + wr * 64 + mi * 16 + lk * 4;
      int c = n0 + wc * 64 + ni * 16 + lr;
#pragma unroll
      for (int j = 0; j < 4; ++j)
        Cf[(size_t)(r + j) * 768 + c] = v[j];
    }
  }
}

// One-shot transpose-convert of all weights: out[N][K] bf16 from in[K][N] f32.
__global__ void tcvt_all(const float* __restrict__ Wg, const float* __restrict__ Ws,
                         const float* __restrict__ wx, const float* __restrict__ wh,
                         const float* __restrict__ pw,
                         u16* __restrict__ W2T, u16* __restrict__ WXT,
                         u16* __restrict__ WHT, u16* __restrict__ PRJ) {
  int idx = blockIdx.x * 256 + threadIdx.x;
  const float* src; u16* dst; int N; int li;
  if (idx < 65536)        { src = Wg; dst = W2T;          N = 256; li = idx; }
  else if (idx < 131072)  { src = Ws; dst = W2T + 65536;  N = 256; li = idx - 65536; }
  else if (idx < 327680)  { src = wx; dst = WXT;          N = 768; li = idx - 131072; }
  else if (idx < 524288)  { src = wh; dst = WHT;          N = 768; li = idx - 327680; }
  else                    { src = pw; dst = PRJ;          N = 256; li = idx - 524288; }
  int n = li >> 8, k = li & 255;
  dst[li] = f2bf(src[(size_t)k * N + n]);
}

// x0 bf16 + virtual sum -> state f32 + GS state half (bf16). float4 loads, 8B stores.
__global__ __launch_bounds__(256)
void prep_x_kernel(const float* __restrict__ nf, u16* __restrict__ X0,
                   float* __restrict__ state, u16* __restrict__ GS) {
  __shared__ f32x4 part[4][64];
  const int b = blockIdx.x, t = threadIdx.x;
  const int c4 = t & 63, sg = t >> 6;
  const f32x4* src = (const f32x4*)(nf + (size_t)b * 48 * 256);
  f32x4 acc = (f32x4){0.f, 0.f, 0.f, 0.f};
  for (int s = sg * 12; s < sg * 12 + 12; ++s) {
    f32x4 v = src[(size_t)s * 64 + c4];
    acc += v;
    u16x4 o = {f2bf(v[0]), f2bf(v[1]), f2bf(v[2]), f2bf(v[3])};
    *(u16x4*)(X0 + ((size_t)b * 48 + s) * 256 + c4 * 4) = o;
  }
  part[sg][c4] = acc;
  __syncthreads();
  if (t < 64) {
    f32x4 r = part[0][t] + part[1][t] + part[2][t] + part[3][t];
#pragma unroll
    for (int j = 0; j < 4; ++j) {
      int d = t * 4 + j;
      state[(size_t)b * 256 + d] = r[j];
      GS[(size_t)b * 512 + 256 + d] = f2bf(r[j]);
    }
  }
}

// GRU elementwise
__global__ void gru_kernel(const float* __restrict__ G1, const float* __restrict__ G2,
                           const float* __restrict__ bx, const float* __restrict__ bh,
                           float* __restrict__ state, u16* __restrict__ GS) {
  const int b = blockIdx.x, d = threadIdx.x;
  const float* g1 = G1 + (size_t)b * 768;
  const float* g2 = G2 + (size_t)b * 768;
  float xz = g1[d] + bx[d], xr = g1[256 + d] + bx[256 + d], xh = g1[512 + d] + bx[512 + d];
  float hz = g2[d] + bh[d], hr = g2[256 + d] + bh[256 + d], hh2 = g2[512 + d] + bh[512 + d];
  float z = 1.f / (1.f + expf(-(xz + hz)));
  float r = 1.f / (1.f + expf(-(xr + hr)));
  float n = tanhf(xh + r * hh2);
  float h0 = state[b * 256 + d];
  float sn = z * h0 + (1.f - z) * n;
  state[b * 256 + d] = sn;
  GS[(size_t)b * 512 + 256 + d] = f2bf(sn);
}

extern "C" void kernel_launch(void* const* d_in, const int* in_sizes, int n_in,
                              void* d_out, int out_size, void* d_ws, size_t ws_size,
                              hipStream_t stream) {
  const float* nf  = (const float*)d_in[0];
  const float* Wg  = (const float*)d_in[2];
  const float* Ws  = (const float*)d_in[3];
  const float* asr = (const float*)d_in[4];
  const float* ads = (const float*)d_in[5];
  const float* wx  = (const float*)d_in[6];
  const float* wh  = (const float*)d_in[7];
  const float* bx  = (const float*)d_in[8];
  const float* bh  = (const float*)d_in[9];
  const float* pw  = (const float*)d_in[10];
  const float* pb  = (const float*)d_in[11];
  float* out = (float*)d_out;

  char* p = (char*)d_ws;
  size_t off = 0;
  auto alloc = [&](size_t bytes) { char* r = p + off; off += (bytes + 255) & ~255ULL; return r; };
  u16* W2T   = (u16*)alloc(512 * 256 * 2);
  u16* WXT   = (u16*)alloc(768 * 256 * 2);
  u16* WHT   = (u16*)alloc(768 * 256 * 2);
  u16* PRJ   = (u16*)alloc(256 * 256 * 2);
  u16* X0    = (u16*)alloc((size_t)98304 * 256 * 2);
  u16* X1    = (u16*)alloc((size_t)98304 * 256 * 2);
  float* G1   = (float*)alloc((size_t)2048 * 768 * 4);
  float* G2   = (float*)alloc((size_t)2048 * 768 * 4);
  u16* GS     = (u16*)alloc((size_t)2048 * 512 * 2);  // [g0 | state] bf16
  float* ST   = (float*)alloc((size_t)2048 * 256 * 4);

  tcvt_all<<<2304, 256, 0, stream>>>(Wg, Ws, wx, wh, pw, W2T, WXT, WHT, PRJ);
  prep_x_kernel<<<2048, 256, 0, stream>>>(nf, X0, ST, GS);

  u16* xc = X0; u16* xn = X1;
  for (int t = 0; t < 4; ++t) {
    // fused: h (incl. virtual row) + attention + g0 + xnext
    fused_step<<<2048, 256, 0, stream>>>(xc, W2T, asr, ads, GS, (t < 3) ? xn : nullptr);
    // GRU gates (both in one launch)
    gemm_gates<<<dim3(16, 12), 256, 0, stream>>>(GS, WXT, WHT, G1, G2);
    gru_kernel<<<2048, 256, 0, stream>>>(G1, G2, bx, bh, ST, GS);
    u16* tmp = xc; xc = xn; xn = tmp;
  }
  // out = state @ proj_w + proj_b
  gemm_bt<2><<<dim3(16, 2), 256, 0, stream>>>(GS + 256, 512, PRJ, out, 256, pb);
}